// Round 5
// baseline (853.061 us; speedup 1.0000x reference)
//
#include <hip/hip_runtime.h>

#define D 128
#define TPAD 132
#define NPB 256          // nodes per bucket (dst >> 8)
#define KMAX 512         // max buckets (n <= 131072)
#define CHUNK 4096       // edges per block in bucket passes

// ---------------- CSR build ----------------
// No per-node global atomics anywhere: bucket histogram is LDS-aggregated over
// 512 counters; per-node counts/offsets are derived per-bucket in LDS.

__global__ __launch_bounds__(256) void zero_int(int* __restrict__ p, int n) {
    int i = blockIdx.x * 256 + threadIdx.x;
    if (i < n) p[i] = 0;
}

__global__ __launch_bounds__(256) void bucket_hist_kernel(const int* __restrict__ dst,
                                                          int* __restrict__ bucket_cnt, int E) {
    __shared__ int scnt[KMAX];
    int t = threadIdx.x;
    for (int i = t; i < KMAX; i += 256) scnt[i] = 0;
    __syncthreads();
    int base = blockIdx.x * CHUNK;
    int nE = min(CHUNK, E - base);
    for (int i = t; i < nE; i += 256)
        atomicAdd(&scnt[dst[base + i] >> 8], 1);
    __syncthreads();
    for (int i = t; i < KMAX; i += 256)
        if (scnt[i]) atomicAdd(&bucket_cnt[i], scnt[i]);
}

// Exclusive scan of bucket_cnt[K] -> bucket_ptr[K+1], bucket_cur[K]=bucket_ptr[K]
__global__ __launch_bounds__(KMAX) void bucket_scan_kernel(const int* __restrict__ bucket_cnt,
                                                           int* __restrict__ bucket_ptr,
                                                           int* __restrict__ bucket_cur,
                                                           int K, int E) {
    __shared__ int sh[KMAX];
    int t = threadIdx.x;
    int v = (t < K) ? bucket_cnt[t] : 0;
    sh[t] = v;
    __syncthreads();
    for (int off = 1; off < KMAX; off <<= 1) {
        int add = (t >= off) ? sh[t - off] : 0;
        __syncthreads();
        sh[t] += add;
        __syncthreads();
    }
    if (t < K) {
        int ex = sh[t] - v;
        bucket_ptr[t] = ex;
        bucket_cur[t] = ex;
    }
    if (t == 0) bucket_ptr[K] = E;
}

// Phase A: partition edges into dst-buckets. Writes are contiguous runs per
// (block,bucket) -> near-full-line writebacks instead of 64B per 4B store.
__global__ __launch_bounds__(256) void bucket_scatter_kernel(const int* __restrict__ src,
                                                             const int* __restrict__ dst,
                                                             int* __restrict__ bucket_cur,
                                                             int2* __restrict__ bdata, int E) {
    __shared__ int sdst[CHUNK];     // 16 KB
    __shared__ int scnt[KMAX];      // 2 KB (counts, then local cursors)
    __shared__ int sbase[KMAX];     // 2 KB
    int t = threadIdx.x;
    int base = blockIdx.x * CHUNK;
    int nE = min(CHUNK, E - base);
    for (int i = t; i < KMAX; i += 256) scnt[i] = 0;
    __syncthreads();
    for (int i = t; i < nE; i += 256) {
        int d = dst[base + i];
        sdst[i] = d;
        atomicAdd(&scnt[d >> 8], 1);
    }
    __syncthreads();
    for (int i = t; i < KMAX; i += 256) {
        int c = scnt[i];
        sbase[i] = c ? atomicAdd(&bucket_cur[i], c) : 0;
        scnt[i] = 0;                // reuse as local cursor
    }
    __syncthreads();
    for (int i = t; i < nE; i += 256) {
        int d = sdst[i];
        int b = d >> 8;
        int pos = sbase[b] + atomicAdd(&scnt[b], 1);
        bdata[pos] = make_int2(src[base + i], d);
    }
}

// Per-bucket: LDS histogram of dst -> per-node count; LDS exclusive scan gives
// row_ptr[node] = bucket_ptr[b] + scan (buckets are contiguous dst ranges, so
// this IS the global CSR offset — no global scan chain needed). Also emits dis.
__global__ __launch_bounds__(256) void csr_count_scan_kernel(const int2* __restrict__ bdata,
                                                             const int* __restrict__ bucket_ptr,
                                                             int* __restrict__ row_ptr,
                                                             float* __restrict__ dis,
                                                             int n, int E, int K) {
    __shared__ int scnt[NPB];
    __shared__ int sh[NPB];
    int b = blockIdx.x;
    int node0 = b << 8;
    int nn = min(NPB, n - node0);
    int t = threadIdx.x;
    scnt[t] = 0;
    __syncthreads();
    int p0 = bucket_ptr[b], p1 = bucket_ptr[b + 1];
    for (int i = p0 + t; i < p1; i += 256)
        atomicAdd(&scnt[bdata[i].y - node0], 1);
    __syncthreads();
    int v = scnt[t];
    sh[t] = v;
    __syncthreads();
    for (int off = 1; off < NPB; off <<= 1) {
        int add = (t >= off) ? sh[t - off] : 0;
        __syncthreads();
        sh[t] += add;
        __syncthreads();
    }
    if (t < nn) {
        row_ptr[node0 + t] = p0 + sh[t] - v;     // exclusive
        dis[node0 + t] = rsqrtf((float)(v + 1)); // +1 self-loop
    }
    if (b == K - 1 && t == 0) row_ptr[n] = E;
}

// Phase B: one block per bucket owns a contiguous csr_src region exclusively;
// per-node cursors live in LDS (no global atomics, no cross-XCD ping-pong).
__global__ __launch_bounds__(256) void csr_fill_kernel(const int2* __restrict__ bdata,
                                                       const int* __restrict__ bucket_ptr,
                                                       const int* __restrict__ row_ptr,
                                                       int* __restrict__ csr_src, int n) {
    __shared__ int cursor[NPB];
    int b = blockIdx.x;
    int node0 = b << 8;
    int nn = min(NPB, n - node0);
    int t = threadIdx.x;
    if (t < nn) cursor[t] = row_ptr[node0 + t];
    __syncthreads();
    int p0 = bucket_ptr[b], p1 = bucket_ptr[b + 1];
    for (int i = p0 + t; i < p1; i += 256) {
        int2 e = bdata[i];
        int pos = atomicAdd(&cursor[e.y - node0], 1);
        csr_src[pos] = e.x;
    }
}

// ---------------- GEMM: C[n x 128] = dis[row] * ((relu?)A[n x 128] @ W[128 x 128]) ----
// Register double-buffered staging: chunk kb+32's global loads are issued
// right after the LDS write of chunk kb, so HBM latency hides under the FMAs.
// __launch_bounds__(256,3): 3 blocks/CU so barrier drains overlap across blocks.

template <bool RELU>
__global__ __launch_bounds__(256, 3) void gemm_kernel(const float* __restrict__ A,
                                                      const float* __restrict__ W,
                                                      const float* __restrict__ dis,
                                                      float* __restrict__ C, int n) {
    __shared__ float sAT[32 * TPAD];   // [k][r], 16.9 KB
    __shared__ float sW[32 * TPAD];    // [k][c], 16.9 KB
    int tid = threadIdx.x;
    int base = blockIdx.x * 128;
    int tx = tid & 15, ty = tid >> 4;

    float acc[8][8];
#pragma unroll
    for (int i = 0; i < 8; ++i)
#pragma unroll
        for (int j = 0; j < 8; ++j) acc[i][j] = 0.f;

    float4 pa[4], pw[4];
    // prefetch chunk kb=0 into registers
#pragma unroll
    for (int it = 0; it < 4; ++it) {
        int idx = it * 1024 + tid * 4;
        int r = idx >> 5, kk = idx & 31;
        int row = base + r;
        pa[it] = (row < n) ? *(const float4*)&A[row * D + kk]
                           : make_float4(0.f, 0.f, 0.f, 0.f);
        int wk = idx >> 7, wc = idx & 127;
        pw[it] = *(const float4*)&W[wk * D + wc];
    }

    for (int kb = 0; kb < 128; kb += 32) {
        __syncthreads();   // protect previous chunk's LDS reads
#pragma unroll
        for (int it = 0; it < 4; ++it) {
            int idx = it * 1024 + tid * 4;
            int r = idx >> 5, kk = idx & 31;
            float4 va = pa[it];
            if (RELU) {
                va.x = fmaxf(va.x, 0.f); va.y = fmaxf(va.y, 0.f);
                va.z = fmaxf(va.z, 0.f); va.w = fmaxf(va.w, 0.f);
            }
            sAT[(kk + 0) * TPAD + r] = va.x;
            sAT[(kk + 1) * TPAD + r] = va.y;
            sAT[(kk + 2) * TPAD + r] = va.z;
            sAT[(kk + 3) * TPAD + r] = va.w;
            int wk = idx >> 7, wc = idx & 127;
            *(float4*)&sW[wk * TPAD + wc] = pw[it];
        }
        __syncthreads();
        // issue next chunk's global loads before the FMA block
        if (kb + 32 < 128) {
#pragma unroll
            for (int it = 0; it < 4; ++it) {
                int idx = it * 1024 + tid * 4;
                int r = idx >> 5, kk = idx & 31;
                int row = base + r;
                pa[it] = (row < n) ? *(const float4*)&A[row * D + kb + 32 + kk]
                                   : make_float4(0.f, 0.f, 0.f, 0.f);
                int wk = idx >> 7, wc = idx & 127;
                pw[it] = *(const float4*)&W[(kb + 32 + wk) * D + wc];
            }
        }
#pragma unroll
        for (int k = 0; k < 32; ++k) {
            float4 a0 = *(const float4*)&sAT[k * TPAD + ty * 8];
            float4 a1 = *(const float4*)&sAT[k * TPAD + ty * 8 + 4];
            float4 w0 = *(const float4*)&sW[k * TPAD + tx * 8];
            float4 w1 = *(const float4*)&sW[k * TPAD + tx * 8 + 4];
            float a[8] = {a0.x, a0.y, a0.z, a0.w, a1.x, a1.y, a1.z, a1.w};
            float w[8] = {w0.x, w0.y, w0.z, w0.w, w1.x, w1.y, w1.z, w1.w};
#pragma unroll
            for (int i = 0; i < 8; ++i)
#pragma unroll
                for (int j = 0; j < 8; ++j) acc[i][j] = fmaf(a[i], w[j], acc[i][j]);
        }
    }

#pragma unroll
    for (int i = 0; i < 8; ++i) {
        int row = base + ty * 8 + i;
        if (row < n) {
            float di = dis[row];
            float4 o0 = make_float4(acc[i][0] * di, acc[i][1] * di,
                                    acc[i][2] * di, acc[i][3] * di);
            float4 o1 = make_float4(acc[i][4] * di, acc[i][5] * di,
                                    acc[i][6] * di, acc[i][7] * di);
            *(float4*)&C[row * D + tx * 8] = o0;
            *(float4*)&C[row * D + tx * 8 + 4] = o1;
        }
    }
}

// ---------------- Aggregation: out[i] = dis_i*(H'[i] + sum_e H'[src_e]) + b ----------
// One wave per node, float2/lane (512 B per gather instruction). Batch-8 gather
// pipeline with next-batch index prefetch: 8 rows (4 KB) in flight per wave and
// index-load latency hidden under the previous batch's gathers.

__global__ __launch_bounds__(256) void aggregate_kernel(const float* __restrict__ Hs,
                                                        const int* __restrict__ row_ptr,
                                                        const int* __restrict__ csr_src,
                                                        const float* __restrict__ dis,
                                                        const float* __restrict__ b,
                                                        float* __restrict__ out, int n) {
    int node = blockIdx.x * 4 + (threadIdx.x >> 6);
    if (node >= n) return;
    int lane = threadIdx.x & 63;
    const float2* __restrict__ H2 = (const float2*)Hs;

    float2 h = H2[(size_t)node * 64 + lane];
    float accx = h.x, accy = h.y;                       // self-loop term H'[i]

    int p0 = row_ptr[node], p1 = row_ptr[node + 1];
    int p = p0;
    int nb8 = (p1 - p0) >> 3;
    if (nb8 > 0) {
        int idx[8];
#pragma unroll
        for (int u = 0; u < 8; ++u) idx[u] = csr_src[p + u];
        for (int bb = 1; bb < nb8; ++bb) {
            int nxt[8];
#pragma unroll
            for (int u = 0; u < 8; ++u) nxt[u] = csr_src[p + 8 + u];   // prefetch
            float2 v[8];
#pragma unroll
            for (int u = 0; u < 8; ++u) v[u] = H2[(size_t)idx[u] * 64 + lane];
#pragma unroll
            for (int u = 0; u < 8; ++u) { accx += v[u].x; accy += v[u].y; }
#pragma unroll
            for (int u = 0; u < 8; ++u) idx[u] = nxt[u];
            p += 8;
        }
        {
            float2 v[8];
#pragma unroll
            for (int u = 0; u < 8; ++u) v[u] = H2[(size_t)idx[u] * 64 + lane];
#pragma unroll
            for (int u = 0; u < 8; ++u) { accx += v[u].x; accy += v[u].y; }
            p += 8;
        }
    }
    // tail (< 8 edges)
    for (; p + 4 <= p1; p += 4) {
        int s0 = csr_src[p + 0];
        int s1 = csr_src[p + 1];
        int s2 = csr_src[p + 2];
        int s3 = csr_src[p + 3];
        float2 v0 = H2[(size_t)s0 * 64 + lane];
        float2 v1 = H2[(size_t)s1 * 64 + lane];
        float2 v2 = H2[(size_t)s2 * 64 + lane];
        float2 v3 = H2[(size_t)s3 * 64 + lane];
        accx += v0.x; accy += v0.y;
        accx += v1.x; accy += v1.y;
        accx += v2.x; accy += v2.y;
        accx += v3.x; accy += v3.y;
    }
    for (; p < p1; ++p) {
        int s = csr_src[p];
        float2 v = H2[(size_t)s * 64 + lane];
        accx += v.x; accy += v.y;
    }

    float di = dis[node];
    float2 bb2 = *(const float2*)(b + 2 * lane);
    float2 o;
    o.x = fmaf(accx, di, bb2.x);
    o.y = fmaf(accy, di, bb2.y);
    ((float2*)(out + (size_t)node * D))[lane] = o;
}

// ---------------- launch ----------------

extern "C" void kernel_launch(void* const* d_in, const int* in_sizes, int n_in,
                              void* d_out, int out_size, void* d_ws, size_t ws_size,
                              hipStream_t stream) {
    const float* x  = (const float*)d_in[0];
    const int*   ei = (const int*)d_in[1];
    const float* W1 = (const float*)d_in[2];
    const float* b1 = (const float*)d_in[3];
    const float* W2 = (const float*)d_in[4];
    const float* b2 = (const float*)d_in[5];
    const float* W3 = (const float*)d_in[6];
    const float* b3 = (const float*)d_in[7];
    float* out = (float*)d_out;

    int n = in_sizes[0] / D;
    int E = in_sizes[1] / 2;
    const int* src = ei;
    const int* dst = ei + E;
    int K = (n + NPB - 1) >> 8;     // buckets

    char* ws = (char*)d_ws;
    float* bufA      = (float*)ws; ws += (size_t)n * D * sizeof(float);
    float* dis       = (float*)ws; ws += (size_t)n * sizeof(float);
    int* row_ptr     = (int*)ws;   ws += (size_t)(n + 1) * sizeof(int);
    int* csr_src     = (int*)ws;   ws += (size_t)E * sizeof(int);
    int* bucket_cnt  = (int*)ws;   ws += KMAX * sizeof(int);
    int* bucket_ptr  = (int*)ws;   ws += (KMAX + 1) * sizeof(int);
    int* bucket_cur  = (int*)ws;   ws += KMAX * sizeof(int);
    int2* bdata      = (int2*)bufA;   // aliases bufA; dead before first GEMM writes it

    int gC = (E + CHUNK - 1) / CHUNK; // 391
    int gM = (n + 127) / 128;         // 782
    int gA = (n + 3) / 4;             // 25000

    // CSR build — no per-node global atomics anywhere.
    zero_int<<<2, 256, 0, stream>>>(bucket_cnt, KMAX);
    bucket_hist_kernel<<<gC, 256, 0, stream>>>(dst, bucket_cnt, E);
    bucket_scan_kernel<<<1, KMAX, 0, stream>>>(bucket_cnt, bucket_ptr, bucket_cur, K, E);
    bucket_scatter_kernel<<<gC, 256, 0, stream>>>(src, dst, bucket_cur, bdata, E);
    csr_count_scan_kernel<<<K, 256, 0, stream>>>(bdata, bucket_ptr, row_ptr, dis, n, E, K);
    csr_fill_kernel<<<K, 256, 0, stream>>>(bdata, bucket_ptr, row_ptr, csr_src, n);

    // Layer 1: H' = dis*(x@W1) -> bufA ; agg+b1 -> out
    gemm_kernel<false><<<gM, 256, 0, stream>>>(x, W1, dis, bufA, n);
    aggregate_kernel<<<gA, 256, 0, stream>>>(bufA, row_ptr, csr_src, dis, b1, out, n);
    // Layer 2: H' = dis*(relu(out)@W2) -> bufA ; agg+b2 -> out
    gemm_kernel<true><<<gM, 256, 0, stream>>>(out, W2, dis, bufA, n);
    aggregate_kernel<<<gA, 256, 0, stream>>>(bufA, row_ptr, csr_src, dis, b2, out, n);
    // Layer 3: H' = dis*(relu(out)@W3) -> bufA ; agg+b3 -> out
    gemm_kernel<true><<<gM, 256, 0, stream>>>(out, W3, dis, bufA, n);
    aggregate_kernel<<<gA, 256, 0, stream>>>(bufA, row_ptr, csr_src, dis, b3, out, n);
}

// Round 6
// 698.336 us; speedup vs baseline: 1.2216x; 1.2216x over previous
//
#include <hip/hip_runtime.h>

#define D 128
#define TPAD 132
#define NPB 256          // nodes per bucket (dst >> 8)
#define KMAX 512         // max buckets (n <= 131072)
#define CHUNK 4096       // edges per block in bucket passes

// ---------------- CSR build ----------------
// No per-node global atomics anywhere: bucket histogram is LDS-aggregated over
// 512 counters; per-node counts/offsets are derived per-bucket in LDS.

__global__ __launch_bounds__(256) void zero_int(int* __restrict__ p, int n) {
    int i = blockIdx.x * 256 + threadIdx.x;
    if (i < n) p[i] = 0;
}

__global__ __launch_bounds__(256) void bucket_hist_kernel(const int* __restrict__ dst,
                                                          int* __restrict__ bucket_cnt, int E) {
    __shared__ int scnt[KMAX];
    int t = threadIdx.x;
    for (int i = t; i < KMAX; i += 256) scnt[i] = 0;
    __syncthreads();
    int base = blockIdx.x * CHUNK;
    int nE = min(CHUNK, E - base);
    for (int i = t; i < nE; i += 256)
        atomicAdd(&scnt[dst[base + i] >> 8], 1);
    __syncthreads();
    for (int i = t; i < KMAX; i += 256)
        if (scnt[i]) atomicAdd(&bucket_cnt[i], scnt[i]);
}

// Exclusive scan of bucket_cnt[K] -> bucket_ptr[K+1], bucket_cur[K]=bucket_ptr[K]
__global__ __launch_bounds__(KMAX) void bucket_scan_kernel(const int* __restrict__ bucket_cnt,
                                                           int* __restrict__ bucket_ptr,
                                                           int* __restrict__ bucket_cur,
                                                           int K, int E) {
    __shared__ int sh[KMAX];
    int t = threadIdx.x;
    int v = (t < K) ? bucket_cnt[t] : 0;
    sh[t] = v;
    __syncthreads();
    for (int off = 1; off < KMAX; off <<= 1) {
        int add = (t >= off) ? sh[t - off] : 0;
        __syncthreads();
        sh[t] += add;
        __syncthreads();
    }
    if (t < K) {
        int ex = sh[t] - v;
        bucket_ptr[t] = ex;
        bucket_cur[t] = ex;
    }
    if (t == 0) bucket_ptr[K] = E;
}

// Phase A: partition edges into dst-buckets. Writes are contiguous runs per
// (block,bucket) -> near-full-line writebacks instead of 64B per 4B store.
__global__ __launch_bounds__(256) void bucket_scatter_kernel(const int* __restrict__ src,
                                                             const int* __restrict__ dst,
                                                             int* __restrict__ bucket_cur,
                                                             int2* __restrict__ bdata, int E) {
    __shared__ int sdst[CHUNK];     // 16 KB
    __shared__ int scnt[KMAX];      // 2 KB (counts, then local cursors)
    __shared__ int sbase[KMAX];     // 2 KB
    int t = threadIdx.x;
    int base = blockIdx.x * CHUNK;
    int nE = min(CHUNK, E - base);
    for (int i = t; i < KMAX; i += 256) scnt[i] = 0;
    __syncthreads();
    for (int i = t; i < nE; i += 256) {
        int d = dst[base + i];
        sdst[i] = d;
        atomicAdd(&scnt[d >> 8], 1);
    }
    __syncthreads();
    for (int i = t; i < KMAX; i += 256) {
        int c = scnt[i];
        sbase[i] = c ? atomicAdd(&bucket_cur[i], c) : 0;
        scnt[i] = 0;                // reuse as local cursor
    }
    __syncthreads();
    for (int i = t; i < nE; i += 256) {
        int d = sdst[i];
        int b = d >> 8;
        int pos = sbase[b] + atomicAdd(&scnt[b], 1);
        bdata[pos] = make_int2(src[base + i], d);
    }
}

// Per-bucket: LDS histogram of dst -> per-node count; LDS exclusive scan gives
// row_ptr[node] = bucket_ptr[b] + scan (buckets are contiguous dst ranges, so
// this IS the global CSR offset — no global scan chain needed). Also emits dis.
__global__ __launch_bounds__(256) void csr_count_scan_kernel(const int2* __restrict__ bdata,
                                                             const int* __restrict__ bucket_ptr,
                                                             int* __restrict__ row_ptr,
                                                             float* __restrict__ dis,
                                                             int n, int E, int K) {
    __shared__ int scnt[NPB];
    __shared__ int sh[NPB];
    int b = blockIdx.x;
    int node0 = b << 8;
    int nn = min(NPB, n - node0);
    int t = threadIdx.x;
    scnt[t] = 0;
    __syncthreads();
    int p0 = bucket_ptr[b], p1 = bucket_ptr[b + 1];
    for (int i = p0 + t; i < p1; i += 256)
        atomicAdd(&scnt[bdata[i].y - node0], 1);
    __syncthreads();
    int v = scnt[t];
    sh[t] = v;
    __syncthreads();
    for (int off = 1; off < NPB; off <<= 1) {
        int add = (t >= off) ? sh[t - off] : 0;
        __syncthreads();
        sh[t] += add;
        __syncthreads();
    }
    if (t < nn) {
        row_ptr[node0 + t] = p0 + sh[t] - v;     // exclusive
        dis[node0 + t] = rsqrtf((float)(v + 1)); // +1 self-loop
    }
    if (b == K - 1 && t == 0) row_ptr[n] = E;
}

// Phase B: one block per bucket owns a contiguous csr_src region exclusively;
// per-node cursors live in LDS (no global atomics, no cross-XCD ping-pong).
__global__ __launch_bounds__(256) void csr_fill_kernel(const int2* __restrict__ bdata,
                                                       const int* __restrict__ bucket_ptr,
                                                       const int* __restrict__ row_ptr,
                                                       int* __restrict__ csr_src, int n) {
    __shared__ int cursor[NPB];
    int b = blockIdx.x;
    int node0 = b << 8;
    int nn = min(NPB, n - node0);
    int t = threadIdx.x;
    if (t < nn) cursor[t] = row_ptr[node0 + t];
    __syncthreads();
    int p0 = bucket_ptr[b], p1 = bucket_ptr[b + 1];
    for (int i = p0 + t; i < p1; i += 256) {
        int2 e = bdata[i];
        int pos = atomicAdd(&cursor[e.y - node0], 1);
        csr_src[pos] = e.x;
    }
}

// ---------------- GEMM: C[n x 128] = dis[row] * ((relu?)A[n x 128] @ W[128 x 128]) ----
// Structure (R6): full A-tile staged in LDS ONCE (k-major, 66 KB, one barrier),
// W streamed from global (64 KB, L2-resident) with register double-buffering of
// 4-k groups. FMA-issue bound: 8192 FMA/thread * 2cyc = 16384 cyc/wave.
// A-frag LDS reads are 16-lane broadcasts (conflict-free).
// __launch_bounds__(256,2): VGPR cap 256 (~150 used, no spill); 2 blocks/CU is
// the LDS limit anyway.

template <bool RELU>
__global__ __launch_bounds__(256, 2) void gemm_kernel(const float* __restrict__ A,
                                                      const float* __restrict__ W,
                                                      const float* __restrict__ dis,
                                                      float* __restrict__ C, int n) {
    __shared__ float sAT[128 * TPAD];   // [k][r], 66 KB
    int tid = threadIdx.x;
    int base = blockIdx.x * 128;
    int tx = tid & 15, ty = tid >> 4;

    // ---- stage A (k-major transpose), one pass ----
    const float4* A4 = (const float4*)A;     // row stride = 32 float4
#pragma unroll
    for (int it = 0; it < 16; ++it) {
        int idx = it * 256 + tid;            // float4 index 0..4095
        int r = idx >> 5, kq = idx & 31;     // row in tile, float4-within-row
        int grow = base + r;
        float4 va = (grow < n) ? A4[(size_t)grow * 32 + kq]
                               : make_float4(0.f, 0.f, 0.f, 0.f);
        if (RELU) {
            va.x = fmaxf(va.x, 0.f); va.y = fmaxf(va.y, 0.f);
            va.z = fmaxf(va.z, 0.f); va.w = fmaxf(va.w, 0.f);
        }
        int k0 = kq * 4;
        sAT[(k0 + 0) * TPAD + r] = va.x;
        sAT[(k0 + 1) * TPAD + r] = va.y;
        sAT[(k0 + 2) * TPAD + r] = va.z;
        sAT[(k0 + 3) * TPAD + r] = va.w;
    }
    __syncthreads();

    float acc[8][8];
#pragma unroll
    for (int i = 0; i < 8; ++i)
#pragma unroll
        for (int j = 0; j < 8; ++j) acc[i][j] = 0.f;

    const float4* W4 = (const float4*)W;     // row stride = 32 float4
    float4 wA[8], wB[8];                     // 4-k groups: w[2*kk], w[2*kk+1]

    // prologue: group k=0..3
#pragma unroll
    for (int kk = 0; kk < 4; ++kk) {
        wA[2 * kk + 0] = W4[(size_t)kk * 32 + tx * 2 + 0];
        wA[2 * kk + 1] = W4[(size_t)kk * 32 + tx * 2 + 1];
    }

#define COMPUTE4(kb, wbuf)                                                     \
    {                                                                          \
        _Pragma("unroll")                                                      \
        for (int kk = 0; kk < 4; ++kk) {                                       \
            int k = (kb) + kk;                                                 \
            float4 a0 = *(const float4*)&sAT[k * TPAD + ty * 8];               \
            float4 a1 = *(const float4*)&sAT[k * TPAD + ty * 8 + 4];           \
            float a[8] = {a0.x, a0.y, a0.z, a0.w, a1.x, a1.y, a1.z, a1.w};     \
            float4 w0 = wbuf[2 * kk + 0], w1 = wbuf[2 * kk + 1];               \
            float w[8] = {w0.x, w0.y, w0.z, w0.w, w1.x, w1.y, w1.z, w1.w};     \
            _Pragma("unroll")                                                  \
            for (int i = 0; i < 8; ++i)                                        \
                _Pragma("unroll")                                              \
                for (int j = 0; j < 8; ++j)                                    \
                    acc[i][j] = fmaf(a[i], w[j], acc[i][j]);                   \
        }                                                                      \
    }

    for (int kb = 0; kb < 128; kb += 8) {
        // prefetch group kb+4 into wB (always valid: kb+4 <= 124)
#pragma unroll
        for (int kk = 0; kk < 4; ++kk) {
            wB[2 * kk + 0] = W4[(size_t)(kb + 4 + kk) * 32 + tx * 2 + 0];
            wB[2 * kk + 1] = W4[(size_t)(kb + 4 + kk) * 32 + tx * 2 + 1];
        }
        COMPUTE4(kb, wA);
        if (kb + 8 < 128) {
            // prefetch group kb+8 into wA
#pragma unroll
            for (int kk = 0; kk < 4; ++kk) {
                wA[2 * kk + 0] = W4[(size_t)(kb + 8 + kk) * 32 + tx * 2 + 0];
                wA[2 * kk + 1] = W4[(size_t)(kb + 8 + kk) * 32 + tx * 2 + 1];
            }
        }
        COMPUTE4(kb + 4, wB);
    }
#undef COMPUTE4

#pragma unroll
    for (int i = 0; i < 8; ++i) {
        int row = base + ty * 8 + i;
        if (row < n) {
            float di = dis[row];
            float4 o0 = make_float4(acc[i][0] * di, acc[i][1] * di,
                                    acc[i][2] * di, acc[i][3] * di);
            float4 o1 = make_float4(acc[i][4] * di, acc[i][5] * di,
                                    acc[i][6] * di, acc[i][7] * di);
            *(float4*)&C[row * D + tx * 8] = o0;
            *(float4*)&C[row * D + tx * 8 + 4] = o1;
        }
    }
}

// ---------------- Aggregation: out[i] = dis_i*(H'[i] + sum_e H'[src_e]) + b ----------
// One wave per node, float2/lane (512 B per gather instruction). Batch-8 gather
// pipeline with next-batch index prefetch.

__global__ __launch_bounds__(256) void aggregate_kernel(const float* __restrict__ Hs,
                                                        const int* __restrict__ row_ptr,
                                                        const int* __restrict__ csr_src,
                                                        const float* __restrict__ dis,
                                                        const float* __restrict__ b,
                                                        float* __restrict__ out, int n) {
    int node = blockIdx.x * 4 + (threadIdx.x >> 6);
    if (node >= n) return;
    int lane = threadIdx.x & 63;
    const float2* __restrict__ H2 = (const float2*)Hs;

    float2 h = H2[(size_t)node * 64 + lane];
    float accx = h.x, accy = h.y;                       // self-loop term H'[i]

    int p0 = row_ptr[node], p1 = row_ptr[node + 1];
    int p = p0;
    int nb8 = (p1 - p0) >> 3;
    if (nb8 > 0) {
        int idx[8];
#pragma unroll
        for (int u = 0; u < 8; ++u) idx[u] = csr_src[p + u];
        for (int bb = 1; bb < nb8; ++bb) {
            int nxt[8];
#pragma unroll
            for (int u = 0; u < 8; ++u) nxt[u] = csr_src[p + 8 + u];   // prefetch
            float2 v[8];
#pragma unroll
            for (int u = 0; u < 8; ++u) v[u] = H2[(size_t)idx[u] * 64 + lane];
#pragma unroll
            for (int u = 0; u < 8; ++u) { accx += v[u].x; accy += v[u].y; }
#pragma unroll
            for (int u = 0; u < 8; ++u) idx[u] = nxt[u];
            p += 8;
        }
        {
            float2 v[8];
#pragma unroll
            for (int u = 0; u < 8; ++u) v[u] = H2[(size_t)idx[u] * 64 + lane];
#pragma unroll
            for (int u = 0; u < 8; ++u) { accx += v[u].x; accy += v[u].y; }
            p += 8;
        }
    }
    // tail (< 8 edges)
    for (; p + 4 <= p1; p += 4) {
        int s0 = csr_src[p + 0];
        int s1 = csr_src[p + 1];
        int s2 = csr_src[p + 2];
        int s3 = csr_src[p + 3];
        float2 v0 = H2[(size_t)s0 * 64 + lane];
        float2 v1 = H2[(size_t)s1 * 64 + lane];
        float2 v2 = H2[(size_t)s2 * 64 + lane];
        float2 v3 = H2[(size_t)s3 * 64 + lane];
        accx += v0.x; accy += v0.y;
        accx += v1.x; accy += v1.y;
        accx += v2.x; accy += v2.y;
        accx += v3.x; accy += v3.y;
    }
    for (; p < p1; ++p) {
        int s = csr_src[p];
        float2 v = H2[(size_t)s * 64 + lane];
        accx += v.x; accy += v.y;
    }

    float di = dis[node];
    float2 bb2 = *(const float2*)(b + 2 * lane);
    float2 o;
    o.x = fmaf(accx, di, bb2.x);
    o.y = fmaf(accy, di, bb2.y);
    ((float2*)(out + (size_t)node * D))[lane] = o;
}

// ---------------- launch ----------------

extern "C" void kernel_launch(void* const* d_in, const int* in_sizes, int n_in,
                              void* d_out, int out_size, void* d_ws, size_t ws_size,
                              hipStream_t stream) {
    const float* x  = (const float*)d_in[0];
    const int*   ei = (const int*)d_in[1];
    const float* W1 = (const float*)d_in[2];
    const float* b1 = (const float*)d_in[3];
    const float* W2 = (const float*)d_in[4];
    const float* b2 = (const float*)d_in[5];
    const float* W3 = (const float*)d_in[6];
    const float* b3 = (const float*)d_in[7];
    float* out = (float*)d_out;

    int n = in_sizes[0] / D;
    int E = in_sizes[1] / 2;
    const int* src = ei;
    const int* dst = ei + E;
    int K = (n + NPB - 1) >> 8;     // buckets

    char* ws = (char*)d_ws;
    float* bufA      = (float*)ws; ws += (size_t)n * D * sizeof(float);
    float* dis       = (float*)ws; ws += (size_t)n * sizeof(float);
    int* row_ptr     = (int*)ws;   ws += (size_t)(n + 1) * sizeof(int);
    int* csr_src     = (int*)ws;   ws += (size_t)E * sizeof(int);
    int* bucket_cnt  = (int*)ws;   ws += KMAX * sizeof(int);
    int* bucket_ptr  = (int*)ws;   ws += (KMAX + 1) * sizeof(int);
    int* bucket_cur  = (int*)ws;   ws += KMAX * sizeof(int);
    int2* bdata      = (int2*)bufA;   // aliases bufA; dead before first GEMM writes it

    int gC = (E + CHUNK - 1) / CHUNK; // 391
    int gM = (n + 127) / 128;         // 782
    int gA = (n + 3) / 4;             // 25000

    // CSR build — no per-node global atomics anywhere.
    zero_int<<<2, 256, 0, stream>>>(bucket_cnt, KMAX);
    bucket_hist_kernel<<<gC, 256, 0, stream>>>(dst, bucket_cnt, E);
    bucket_scan_kernel<<<1, KMAX, 0, stream>>>(bucket_cnt, bucket_ptr, bucket_cur, K, E);
    bucket_scatter_kernel<<<gC, 256, 0, stream>>>(src, dst, bucket_cur, bdata, E);
    csr_count_scan_kernel<<<K, 256, 0, stream>>>(bdata, bucket_ptr, row_ptr, dis, n, E, K);
    csr_fill_kernel<<<K, 256, 0, stream>>>(bdata, bucket_ptr, row_ptr, csr_src, n);

    // Layer 1: H' = dis*(x@W1) -> bufA ; agg+b1 -> out
    gemm_kernel<false><<<gM, 256, 0, stream>>>(x, W1, dis, bufA, n);
    aggregate_kernel<<<gA, 256, 0, stream>>>(bufA, row_ptr, csr_src, dis, b1, out, n);
    // Layer 2: H' = dis*(relu(out)@W2) -> bufA ; agg+b2 -> out
    gemm_kernel<true><<<gM, 256, 0, stream>>>(out, W2, dis, bufA, n);
    aggregate_kernel<<<gA, 256, 0, stream>>>(bufA, row_ptr, csr_src, dis, b2, out, n);
    // Layer 3: H' = dis*(relu(out)@W3) -> bufA ; agg+b3 -> out
    gemm_kernel<true><<<gM, 256, 0, stream>>>(out, W3, dis, bufA, n);
    aggregate_kernel<<<gA, 256, 0, stream>>>(bufA, row_ptr, csr_src, dis, b3, out, n);
}